// Round 4
// baseline (6984.434 us; speedup 1.0000x reference)
//
#include <hip/hip_runtime.h>

// Problem dims (hardcoded per reference)
constexpr int kB   = 64;    // batch
constexpr int kM   = 32;    // rows
constexpr int kN   = 32;    // cols
constexpr int kD   = 256;   // input/vocab dim
constexpr int kH   = 256;   // hidden
constexpr int kHin = 768;   // D + 2H
constexpr int kG5  = 1280;  // 5H

__device__ __forceinline__ float sigm(float x) { return 1.f / (1.f + expf(-x)); }

// One kernel launch per anti-diagonal d. Block = (cell, 4-batch slice).
// Inputs fp32, OUTPUT fp32 (reference dtypes; round-3 post-mortem).
// The block computes the full gate row (4 x 1280, K=768), then cell update,
// LayerNorm (block-wide reduce, blockDim == H == 256), head GEMM, fp32 store.
// h/c state fp32 in ws, parity double-buffered by diagonal; both neighbors of
// a cell on diagonal d live on diagonal d-1, so parity buffering is exact.

__global__ __launch_bounds__(256, 2)
void slstm_diag(int d,
                const float* __restrict__ x,
                const float* __restrict__ Wg,
                const float* __restrict__ bg,
                const float* __restrict__ lns,
                const float* __restrict__ lnb,
                const float* __restrict__ Wh,
                const float* __restrict__ bh,
                const float* __restrict__ hinit,
                float* __restrict__ out,
                float* __restrict__ h_bufs,
                float* __restrict__ c_bufs)
{
    __shared__ float xin_s[4 * 768];     // staged A-rows; reused as hn_s later
    __shared__ float gates_s[4 * 1280];  // gate pre-activations
    __shared__ float red[8];

    const int tid = threadIdx.x;
    const int ilo = max(0, d - (kN - 1));
    const int cell = blockIdx.x >> 4;
    const int i = ilo + cell;
    const int j = d - i;
    const int b0 = (blockIdx.x & 15) * 4;

    const int plane = kM * kB * kH;
    const float* h_prev = h_bufs + ((d + 1) & 1) * plane;
    float*       h_cur  = h_bufs + (d & 1) * plane;
    const float* c_prev = c_bufs + ((d + 1) & 1) * plane;
    float*       c_cur  = c_bufs + (d & 1) * plane;

    // ---- stage xin[4][768] = [x | h_left | h_up] ----
    for (int idx = tid; idx < 4 * 768; idx += 256) {
        const int bl = idx / 768;
        const int k  = idx - bl * 768;
        const int b  = b0 + bl;
        float v;
        if (k < kD) {
            v = x[(((size_t)b * kM + i) * kN + j) * kD + k];
        } else if (k < kD + kH) {
            const int u = k - kD;
            v = (j > 0) ? h_prev[((size_t)i * kB + b) * kH + u] : hinit[u];
        } else {
            const int u = k - kD - kH;
            v = (i > 0) ? h_prev[((size_t)(i - 1) * kB + b) * kH + u] : hinit[u];
        }
        xin_s[idx] = v;
    }
    __syncthreads();

    // ---- gate GEMM: thread t owns cols {4t..4t+3, 1024+t} x 4 batches ----
    float acc[4][5];
    #pragma unroll
    for (int bl = 0; bl < 4; ++bl)
        #pragma unroll
        for (int c = 0; c < 5; ++c) acc[bl][c] = 0.f;

    const int c4 = tid * 4;
    const int c1 = 1024 + tid;

    for (int k0 = 0; k0 < kHin; k0 += 4) {
        float Aa[4][4];
        #pragma unroll
        for (int bl = 0; bl < 4; ++bl) {
            const float4 t4 = *(const float4*)&xin_s[bl * 768 + k0];
            Aa[bl][0] = t4.x; Aa[bl][1] = t4.y; Aa[bl][2] = t4.z; Aa[bl][3] = t4.w;
        }
        #pragma unroll
        for (int kk = 0; kk < 4; ++kk) {
            const float* wr = Wg + (size_t)(k0 + kk) * kG5;
            const float4 w = *(const float4*)(wr + c4);
            const float w4 = wr[c1];
            #pragma unroll
            for (int bl = 0; bl < 4; ++bl) {
                const float a = Aa[bl][kk];
                acc[bl][0] = fmaf(a, w.x, acc[bl][0]);
                acc[bl][1] = fmaf(a, w.y, acc[bl][1]);
                acc[bl][2] = fmaf(a, w.z, acc[bl][2]);
                acc[bl][3] = fmaf(a, w.w, acc[bl][3]);
                acc[bl][4] = fmaf(a, w4,  acc[bl][4]);
            }
        }
    }
    #pragma unroll
    for (int bl = 0; bl < 4; ++bl) {
        float4 o; o.x = acc[bl][0]; o.y = acc[bl][1]; o.z = acc[bl][2]; o.w = acc[bl][3];
        *(float4*)&gates_s[bl * 1280 + c4] = o;
        gates_s[bl * 1280 + c1] = acc[bl][4];
    }
    __syncthreads();

    // ---- phase B: cell update + LN + h_new (thread t = hidden unit u) ----
    const int u = tid;
    const float bg0 = bg[u];
    const float bg1 = bg[kH + u];
    const float bg2 = bg[2 * kH + u];
    const float bg3 = bg[3 * kH + u];
    const float bg4 = bg[4 * kH + u];
    const float lnsc = lns[u];
    const float lnbi = lnb[u];
    const int lane = tid & 63, wid = tid >> 6;
    float* hn_s = xin_s;   // xin dead; reuse for h_new rows

    for (int bl = 0; bl < 4; ++bl) {
        const int b = b0 + bl;
        const float fc = gates_s[bl * 1280 + u] + bg0;
        const float fr = gates_s[bl * 1280 + kH + u] + bg1;
        const float ig = gates_s[bl * 1280 + 2 * kH + u] + bg2;
        const float og = gates_s[bl * 1280 + 3 * kH + u] + bg3;
        const float gg = gates_s[bl * 1280 + 4 * kH + u] + bg4;
        const float cl = (j > 0) ? c_prev[((size_t)i * kB + b) * kH + u] : 0.f;
        const float cu = (i > 0) ? c_prev[((size_t)(i - 1) * kB + b) * kH + u] : 0.f;

        const float cell_v = sigm(fc) * cl + sigm(fr) * cu + sigm(ig) * tanhf(gg);
        c_cur[((size_t)i * kB + b) * kH + u] = cell_v;

        float s = cell_v, s2 = cell_v * cell_v;
        #pragma unroll
        for (int off = 32; off; off >>= 1) {
            s  += __shfl_down(s,  off, 64);
            s2 += __shfl_down(s2, off, 64);
        }
        if (lane == 0) { red[wid] = s; red[4 + wid] = s2; }
        __syncthreads();
        const float sum = red[0] + red[1] + red[2] + red[3];
        const float sq  = red[4] + red[5] + red[6] + red[7];
        __syncthreads();   // red reused next bl

        const float mu   = sum * (1.f / kH);
        const float var  = sq * (1.f / kH) - mu * mu;
        const float rstd = rsqrtf(var + 1e-6f);
        const float hv   = sigm(og) * tanhf((cell_v - mu) * rstd * lnsc + lnbi);
        h_cur[((size_t)i * kB + b) * kH + u] = hv;
        hn_s[bl * 256 + u] = hv;
    }
    __syncthreads();

    // ---- head GEMM: logits[b][u] = b_head[u] + sum_k hn[b][k] * Wh[k][u] ----
    const float bhv = bh[u];
    float ah[4] = {bhv, bhv, bhv, bhv};
    for (int k0 = 0; k0 < kH; k0 += 4) {
        float Hn[4][4];
        #pragma unroll
        for (int bl = 0; bl < 4; ++bl) {
            const float4 t4 = *(const float4*)&hn_s[bl * 256 + k0];
            Hn[bl][0] = t4.x; Hn[bl][1] = t4.y; Hn[bl][2] = t4.z; Hn[bl][3] = t4.w;
        }
        #pragma unroll
        for (int kk = 0; kk < 4; ++kk) {
            const float w = Wh[(size_t)(k0 + kk) * kD + u];
            #pragma unroll
            for (int bl = 0; bl < 4; ++bl)
                ah[bl] = fmaf(Hn[bl][kk], w, ah[bl]);
        }
    }
    #pragma unroll
    for (int bl = 0; bl < 4; ++bl) {
        const int b = b0 + bl;
        out[(((size_t)b * kM + i) * kN + j) * kD + u] = ah[bl];
    }
}

extern "C" void kernel_launch(void* const* d_in, const int* in_sizes, int n_in,
                              void* d_out, int out_size, void* d_ws, size_t ws_size,
                              hipStream_t stream) {
    const float* x     = (const float*)d_in[0];
    const float* Wg    = (const float*)d_in[1];
    const float* bg    = (const float*)d_in[2];
    const float* lns   = (const float*)d_in[3];
    const float* lnb   = (const float*)d_in[4];
    const float* Wh    = (const float*)d_in[5];
    const float* bh    = (const float*)d_in[6];
    const float* hinit = (const float*)d_in[7];
    float* out = (float*)d_out;

    float* h_bufs = (float*)d_ws;                       // 2 planes x 2 MiB
    float* c_bufs = h_bufs + 2 * (kM * kB * kH);        // 2 planes x 2 MiB
    // total ws use: 8 MiB fp32

    for (int d = 0; d < kM + kN - 1; ++d) {
        const int ilo = max(0, d - (kN - 1));
        const int ihi = min(d, kM - 1);
        const int ncell = ihi - ilo + 1;
        const int njobs = ncell * 16;
        hipLaunchKernelGGL(slstm_diag, dim3(njobs), dim3(256), 0, stream,
                           d, x, Wg, bg, lns, lnb, Wh, bh, hinit, out,
                           h_bufs, c_bufs);
    }
}

// Round 5
// 5238.810 us; speedup vs baseline: 1.3332x; 1.3332x over previous
//
#include <hip/hip_runtime.h>

// Problem dims (hardcoded per reference)
constexpr int kB   = 64;    // batch
constexpr int kM   = 32;    // rows
constexpr int kN   = 32;    // cols
constexpr int kD   = 256;   // input/vocab dim
constexpr int kH   = 256;   // hidden
constexpr int kHin = 768;   // D + 2H
constexpr int kG5  = 1280;  // 5H

typedef __attribute__((ext_vector_type(8)))  short bf16x8;
typedef __attribute__((ext_vector_type(16))) float f32x16;

__device__ __forceinline__ float bu2f(unsigned short u) {
    return __uint_as_float(((unsigned)u) << 16);
}
__device__ __forceinline__ unsigned short f2bu(float f) {
    unsigned u = __float_as_uint(f);
    return (unsigned short)((u + 0x7FFF + ((u >> 16) & 1)) >> 16);   // RNE
}
__device__ __forceinline__ void split1(float a, unsigned short& hi, unsigned short& lo) {
    hi = f2bu(a);
    lo = f2bu(a - bu2f(hi));     // |residual after lo| <= 2^-18 |a|
}
__device__ __forceinline__ float sigm(float x) { return 1.f / (1.f + expf(-x)); }

// ---------------------------------------------------------------------------
// Prep 1: swizzle Wg (fp32 [768][1280]) into MFMA-B-fragment-contiguous bf16
// hi/lo panels. Fragment for v_mfma_f32_32x32x16_bf16 B-operand: lane l holds
// B[k = (l>>5)*8 + j][n = l&31], j=0..7. Panel index: g = ((ntile*48 + s)*64
// + lane), element j; k = s*16 + (l>>5)*8 + j, n = ntile*32 + (l&31).
// 40 ntiles x 48 ksteps x 64 lanes = 122880 groups of 8.
// ---------------------------------------------------------------------------
__global__ void prep_w(const float* __restrict__ Wg,
                       unsigned short* __restrict__ whi,
                       unsigned short* __restrict__ wlo) {
    const int t = blockIdx.x * 256 + threadIdx.x;     // 0..122879
    const int lane = t & 63;
    const int rest = t >> 6;
    const int s = rest % 48;
    const int ntile = rest / 48;
    const int n = ntile * 32 + (lane & 31);
    const int kb = s * 16 + (lane >> 5) * 8;
    unsigned short h8[8], l8[8];
    #pragma unroll
    for (int j = 0; j < 8; ++j) {
        const float a = Wg[(size_t)(kb + j) * kG5 + n];
        split1(a, h8[j], l8[j]);
    }
    *(bf16x8*)(whi + (size_t)t * 8) = *(const bf16x8*)h8;
    *(bf16x8*)(wlo + (size_t)t * 8) = *(const bf16x8*)l8;
}

// Prep 2: hinit fp32[256] -> hi/lo bf16
__global__ void prep_h0(const float* __restrict__ hinit,
                        unsigned short* __restrict__ h0h,
                        unsigned short* __restrict__ h0l) {
    const int t = threadIdx.x;
    unsigned short h, l;
    split1(hinit[t], h, l);
    h0h[t] = h; h0l[t] = l;
}

// ---------------------------------------------------------------------------
// Phase A (per diagonal): gates[i][b][col] = xin[b][:] @ Wg[:][col]
// Block = (cell-pair p, 128-col chunk nc). M = 128 rows = 2 cells x 64 batch.
// 3-pass hi/lo bf16 split MFMA, fp32 acc. A staged in LDS per BK=32 chunk
// (k-chunks align with the x / h_left / h_up region boundaries).
// ---------------------------------------------------------------------------
__global__ __launch_bounds__(256)
void gate_mfma(int d,
               const float* __restrict__ x,
               const unsigned short* __restrict__ whi,
               const unsigned short* __restrict__ wlo,
               const unsigned short* __restrict__ hhi,
               const unsigned short* __restrict__ hlo,
               const unsigned short* __restrict__ h0h,
               const unsigned short* __restrict__ h0l,
               float* __restrict__ gates) {
    __shared__ unsigned short As_hi[128 * 40];   // pitch 40 bf16 (2-way banks)
    __shared__ unsigned short As_lo[128 * 40];

    const int tid = threadIdx.x;
    const int ilo = max(0, d - (kN - 1));
    const int ihi = min(d, kM - 1);
    const int p  = blockIdx.x / 10;
    const int nc = blockIdx.x % 10;
    const int w = tid >> 6, lane = tid & 63;
    const int hp = (d + 1) & 1;                  // h plane written at diag d-1

    const int ms = tid >> 3;                     // staging: m = g*32 + ms
    const int k4 = (tid & 7) * 4;

    f32x16 acc[2][2];
    #pragma unroll
    for (int mt = 0; mt < 2; ++mt)
        #pragma unroll
        for (int nt = 0; nt < 2; ++nt)
            #pragma unroll
            for (int r = 0; r < 16; ++r) acc[mt][nt][r] = 0.f;

    const int ntile_g0 = nc * 4 + (w >> 1) * 2;

    bf16x8 wh_c[2][2], wl_c[2][2];   // [k-half][nt]
    #pragma unroll
    for (int kh = 0; kh < 2; ++kh)
        #pragma unroll
        for (int nt = 0; nt < 2; ++nt) {
            const size_t g = (size_t)((ntile_g0 + nt) * 48 + kh) * 64 + lane;
            wh_c[kh][nt] = *(const bf16x8*)(whi + g * 8);
            wl_c[kh][nt] = *(const bf16x8*)(wlo + g * 8);
        }

    for (int kc = 0; kc < 24; ++kc) {
        // ---- stage A chunk: rows 0..127, k = kc*32 .. +31 ----
        #pragma unroll
        for (int g = 0; g < 4; ++g) {
            const int m = g * 32 + ms;
            const int b = m & 63;
            const int ic = min(ilo + 2 * p + (m >> 6), ihi);
            const int jc = d - ic;
            ushort4 hi4, lo4;
            if (kc < 8) {
                const float4 v = *(const float4*)(x + (((size_t)b * kM + ic) * kN + jc) * kD + kc * 32 + k4);
                split1(v.x, hi4.x, lo4.x); split1(v.y, hi4.y, lo4.y);
                split1(v.z, hi4.z, lo4.z); split1(v.w, hi4.w, lo4.w);
            } else if (kc < 16) {
                const int u = (kc - 8) * 32 + k4;
                if (jc > 0) {
                    const size_t o = (((size_t)hp * kM + ic) * kB + b) * kH + u;
                    hi4 = *(const ushort4*)(hhi + o); lo4 = *(const ushort4*)(hlo + o);
                } else {
                    hi4 = *(const ushort4*)(h0h + u); lo4 = *(const ushort4*)(h0l + u);
                }
            } else {
                const int u = (kc - 16) * 32 + k4;
                if (ic > 0) {
                    const size_t o = (((size_t)hp * kM + (ic - 1)) * kB + b) * kH + u;
                    hi4 = *(const ushort4*)(hhi + o); lo4 = *(const ushort4*)(hlo + o);
                } else {
                    hi4 = *(const ushort4*)(h0h + u); lo4 = *(const ushort4*)(h0l + u);
                }
            }
            *(ushort4*)&As_hi[m * 40 + k4] = hi4;
            *(ushort4*)&As_lo[m * 40 + k4] = lo4;
        }

        // ---- prefetch next chunk's W fragments (global, independent) ----
        bf16x8 wh_n[2][2], wl_n[2][2];
        if (kc < 23) {
            #pragma unroll
            for (int kh = 0; kh < 2; ++kh)
                #pragma unroll
                for (int nt = 0; nt < 2; ++nt) {
                    const size_t g = (size_t)((ntile_g0 + nt) * 48 + (kc + 1) * 2 + kh) * 64 + lane;
                    wh_n[kh][nt] = *(const bf16x8*)(whi + g * 8);
                    wl_n[kh][nt] = *(const bf16x8*)(wlo + g * 8);
                }
        }
        __syncthreads();

        // ---- compute: 2 K=16 steps, 2 m-tiles x 2 n-tiles, 3 passes ----
        #pragma unroll
        for (int kh = 0; kh < 2; ++kh) {
            bf16x8 ah[2], al[2];
            const int koff = kh * 16 + (lane >> 5) * 8;
            #pragma unroll
            for (int mt = 0; mt < 2; ++mt) {
                const int m = (w & 1) * 64 + mt * 32 + (lane & 31);
                ah[mt] = *(const bf16x8*)&As_hi[m * 40 + koff];
                al[mt] = *(const bf16x8*)&As_lo[m * 40 + koff];
            }
            #pragma unroll
            for (int mt = 0; mt < 2; ++mt)
                #pragma unroll
                for (int nt = 0; nt < 2; ++nt) {
                    acc[mt][nt] = __builtin_amdgcn_mfma_f32_32x32x16_bf16(ah[mt], wh_c[kh][nt], acc[mt][nt], 0, 0, 0);
                    acc[mt][nt] = __builtin_amdgcn_mfma_f32_32x32x16_bf16(ah[mt], wl_c[kh][nt], acc[mt][nt], 0, 0, 0);
                    acc[mt][nt] = __builtin_amdgcn_mfma_f32_32x32x16_bf16(al[mt], wh_c[kh][nt], acc[mt][nt], 0, 0, 0);
                }
        }
        __syncthreads();
        #pragma unroll
        for (int kh = 0; kh < 2; ++kh)
            #pragma unroll
            for (int nt = 0; nt < 2; ++nt) { wh_c[kh][nt] = wh_n[kh][nt]; wl_c[kh][nt] = wl_n[kh][nt]; }
    }

    // ---- epilogue: C/D layout col=lane&31, row=(r&3)+8*(r>>2)+4*(lane>>5) ----
    const int ic = ilo + 2 * p + (w & 1);
    if (ic <= ihi) {
        #pragma unroll
        for (int mt = 0; mt < 2; ++mt)
            #pragma unroll
            for (int nt = 0; nt < 2; ++nt) {
                const int col = nc * 128 + ((w >> 1) * 2 + nt) * 32 + (lane & 31);
                #pragma unroll
                for (int r = 0; r < 16; ++r) {
                    const int mrow = (r & 3) + 8 * (r >> 2) + 4 * (lane >> 5);
                    const int b = mt * 32 + mrow;
                    gates[((size_t)ic * kB + b) * kG5 + col] = acc[mt][nt][r];
                }
            }
    }
}

// ---------------------------------------------------------------------------
// Phase B (per diagonal): cell update + LayerNorm + h_new + head GEMM.
// Block = (cell, 8-batch slice), 256 threads (thread = hidden unit u).
// Head GEMM uses per-wave register-resident hn + v_readlane broadcast.
// ---------------------------------------------------------------------------
__global__ __launch_bounds__(256)
void cell_head(int d,
               const float* __restrict__ bg,
               const float* __restrict__ lns,
               const float* __restrict__ lnb,
               const float* __restrict__ Wh,
               const float* __restrict__ bh,
               const float* __restrict__ gates,
               float* __restrict__ c_bufs,
               unsigned short* __restrict__ hhi,
               unsigned short* __restrict__ hlo,
               float* __restrict__ out) {
    __shared__ float hn_s[8 * 256];
    __shared__ float red[8];

    const int tid = threadIdx.x;
    const int ilo = max(0, d - (kN - 1));
    const int i = ilo + (blockIdx.x >> 3);
    const int j = d - i;
    const int b0 = (blockIdx.x & 7) * 8;
    const int plane = kM * kB * kH;
    const float* c_prev = c_bufs + ((d + 1) & 1) * plane;
    float*       c_cur  = c_bufs + (d & 1) * plane;
    const int hp = d & 1;

    const int u = tid;
    const float bg0 = bg[u];
    const float bg1 = bg[kH + u];
    const float bg2 = bg[2 * kH + u];
    const float bg3 = bg[3 * kH + u];
    const float bg4 = bg[4 * kH + u];
    const float lnsc = lns[u];
    const float lnbi = lnb[u];
    const int lane = tid & 63, wid = tid >> 6;

    for (int bl = 0; bl < 8; ++bl) {
        const int b = b0 + bl;
        const float* grow = gates + ((size_t)i * kB + b) * kG5;
        const float fc = grow[u] + bg0;
        const float fr = grow[kH + u] + bg1;
        const float ig = grow[2 * kH + u] + bg2;
        const float og = grow[3 * kH + u] + bg3;
        const float gg = grow[4 * kH + u] + bg4;
        const float cl = (j > 0) ? c_prev[((size_t)i * kB + b) * kH + u] : 0.f;
        const float cu = (i > 0) ? c_prev[((size_t)(i - 1) * kB + b) * kH + u] : 0.f;

        const float cell_v = sigm(fc) * cl + sigm(fr) * cu + sigm(ig) * tanhf(gg);
        c_cur[((size_t)i * kB + b) * kH + u] = cell_v;

        float s = cell_v, s2 = cell_v * cell_v;
        #pragma unroll
        for (int off = 32; off; off >>= 1) {
            s  += __shfl_down(s,  off, 64);
            s2 += __shfl_down(s2, off, 64);
        }
        if (lane == 0) { red[wid] = s; red[4 + wid] = s2; }
        __syncthreads();
        const float sum = red[0] + red[1] + red[2] + red[3];
        const float sq  = red[4] + red[5] + red[6] + red[7];
        __syncthreads();

        const float mu   = sum * (1.f / kH);
        const float var  = sq * (1.f / kH) - mu * mu;
        const float rstd = rsqrtf(var + 1e-6f);
        const float hv   = sigm(og) * tanhf((cell_v - mu) * rstd * lnsc + lnbi);
        hn_s[bl * 256 + u] = hv;
        unsigned short hb, lb;
        split1(hv, hb, lb);
        const size_t ho = (((size_t)hp * kM + i) * kB + b) * kH + u;
        hhi[ho] = hb; hlo[ho] = lb;
    }
    __syncthreads();

    // head: per-wave register copy of hn, readlane broadcast in k-loop
    float hr[8][4];
    #pragma unroll
    for (int bl = 0; bl < 8; ++bl)
        #pragma unroll
        for (int k6 = 0; k6 < 4; ++k6)
            hr[bl][k6] = hn_s[bl * 256 + k6 * 64 + lane];

    const float bhv = bh[u];
    float ah[8];
    #pragma unroll
    for (int bl = 0; bl < 8; ++bl) ah[bl] = bhv;

    #pragma unroll
    for (int k6 = 0; k6 < 4; ++k6) {
        for (int kl = 0; kl < 64; ++kl) {
            const float wv = Wh[(size_t)(k6 * 64 + kl) * kD + u];
            #pragma unroll
            for (int bl = 0; bl < 8; ++bl) {
#if __has_builtin(__builtin_amdgcn_readlane)
                const float hvv = __int_as_float(__builtin_amdgcn_readlane(__float_as_int(hr[bl][k6]), kl));
#else
                const float hvv = __shfl(hr[bl][k6], kl, 64);
#endif
                ah[bl] = fmaf(hvv, wv, ah[bl]);
            }
        }
    }
    #pragma unroll
    for (int bl = 0; bl < 8; ++bl) {
        const int b = b0 + bl;
        out[(((size_t)b * kM + i) * kN + j) * kD + u] = ah[bl];
    }
}

extern "C" void kernel_launch(void* const* d_in, const int* in_sizes, int n_in,
                              void* d_out, int out_size, void* d_ws, size_t ws_size,
                              hipStream_t stream) {
    const float* x     = (const float*)d_in[0];
    const float* Wg    = (const float*)d_in[1];
    const float* bg    = (const float*)d_in[2];
    const float* lns   = (const float*)d_in[3];
    const float* lnb   = (const float*)d_in[4];
    const float* Wh    = (const float*)d_in[5];
    const float* bh    = (const float*)d_in[6];
    const float* hinit = (const float*)d_in[7];
    float* out = (float*)d_out;

    // ws layout (byte offsets, all 16B-aligned); total ~21.8 MB
    char* wsb = (char*)d_ws;
    float*          gates  = (float*)(wsb);                              // 10,485,760 B
    float*          c_bufs = (float*)(wsb + 10485760);                   //  4,194,304 B
    unsigned short* hhi    = (unsigned short*)(wsb + 14680064);          //  2,097,152 B
    unsigned short* hlo    = (unsigned short*)(wsb + 16777216);          //  2,097,152 B
    unsigned short* whi    = (unsigned short*)(wsb + 18874368);          //  1,966,080 B
    unsigned short* wlo    = (unsigned short*)(wsb + 20840448);          //  1,966,080 B
    unsigned short* h0h    = (unsigned short*)(wsb + 22806528);          //        512 B
    unsigned short* h0l    = (unsigned short*)(wsb + 22807040);          //        512 B

    hipLaunchKernelGGL(prep_w, dim3(480), dim3(256), 0, stream, Wg, whi, wlo);
    hipLaunchKernelGGL(prep_h0, dim3(1), dim3(256), 0, stream, hinit, h0h, h0l);

    for (int d = 0; d < kM + kN - 1; ++d) {
        const int ilo = max(0, d - (kN - 1));
        const int ihi = min(d, kM - 1);
        const int ncell = ihi - ilo + 1;
        const int npairs = (ncell + 1) >> 1;
        hipLaunchKernelGGL(gate_mfma, dim3(npairs * 10), dim3(256), 0, stream,
                           d, x, whi, wlo, hhi, hlo, h0h, h0l, gates);
        hipLaunchKernelGGL(cell_head, dim3(ncell * 8), dim3(256), 0, stream,
                           d, bg, lns, lnb, Wh, bh, gates, c_bufs, hhi, hlo, out);
    }
}

// Round 6
// 3171.934 us; speedup vs baseline: 2.2019x; 1.6516x over previous
//
#include <hip/hip_runtime.h>

// Problem dims (hardcoded per reference)
constexpr int kB   = 64;    // batch
constexpr int kM   = 32;    // rows
constexpr int kN   = 32;    // cols
constexpr int kD   = 256;   // input/vocab dim
constexpr int kH   = 256;   // hidden
constexpr int kHin = 768;   // D + 2H
constexpr int kG5  = 1280;  // 5H

typedef __attribute__((ext_vector_type(8)))  short bf16x8;
typedef __attribute__((ext_vector_type(16))) float f32x16;

__device__ __forceinline__ float bu2f(unsigned short u) {
    return __uint_as_float(((unsigned)u) << 16);
}
__device__ __forceinline__ unsigned short f2bu(float f) {
    unsigned u = __float_as_uint(f);
    return (unsigned short)((u + 0x7FFF + ((u >> 16) & 1)) >> 16);   // RNE
}
__device__ __forceinline__ void split1(float a, unsigned short& hi, unsigned short& lo) {
    hi = f2bu(a);
    lo = f2bu(a - bu2f(hi));     // |residual after lo| <= 2^-18 |a|
}
__device__ __forceinline__ float sigm(float x) { return 1.f / (1.f + expf(-x)); }

// ---------------------------------------------------------------------------
// Prep 1: swizzle Wg (fp32 [768][1280]) into MFMA-B-fragment-contiguous bf16
// hi/lo panels. B-frag for v_mfma_f32_32x32x16_bf16: lane l holds
// B[k=(l>>5)*8+j][n=l&31]. Panel: g = ((ntile*48 + s)*64 + lane), elem j;
// k = s*16 + (l>>5)*8 + j, n = ntile*32 + (l&31). 40x48x64 groups of 8.
// ---------------------------------------------------------------------------
__global__ void prep_w(const float* __restrict__ Wg,
                       unsigned short* __restrict__ whi,
                       unsigned short* __restrict__ wlo) {
    const int t = blockIdx.x * 256 + threadIdx.x;     // 0..122879
    const int lane = t & 63;
    const int rest = t >> 6;
    const int s = rest % 48;
    const int ntile = rest / 48;
    const int n = ntile * 32 + (lane & 31);
    const int kb = s * 16 + (lane >> 5) * 8;
    unsigned short h8[8], l8[8];
    #pragma unroll
    for (int j = 0; j < 8; ++j) {
        const float a = Wg[(size_t)(kb + j) * kG5 + n];
        split1(a, h8[j], l8[j]);
    }
    *(bf16x8*)(whi + (size_t)t * 8) = *(const bf16x8*)h8;
    *(bf16x8*)(wlo + (size_t)t * 8) = *(const bf16x8*)l8;
}

__global__ void prep_h0(const float* __restrict__ hinit,
                        unsigned short* __restrict__ h0h,
                        unsigned short* __restrict__ h0l) {
    const int t = threadIdx.x;
    unsigned short h, l;
    split1(hinit[t], h, l);
    h0h[t] = h; h0l[t] = l;
}

// ---------------------------------------------------------------------------
// Phase A (per diagonal): gates[i][b][col] = xin[b][:] @ Wg[:][col]
// Block = (cell, 64-col chunk nc). M = 64 (batch), N = 64, one 32x32 MFMA
// tile per wave. blockIdx = cell*20 + nc: same-nc blocks land on ~2 XCDs
// (round-robin %8, stride 20) -> W L2 locality. 3-pass hi/lo split, fp32 acc.
// ---------------------------------------------------------------------------
__global__ __launch_bounds__(256)
void gate_mfma(int d,
               const float* __restrict__ x,
               const unsigned short* __restrict__ whi,
               const unsigned short* __restrict__ wlo,
               const unsigned short* __restrict__ hhi,
               const unsigned short* __restrict__ hlo,
               const unsigned short* __restrict__ h0h,
               const unsigned short* __restrict__ h0l,
               float* __restrict__ gates) {
    __shared__ unsigned short As_hi[64 * 40];   // pitch 40 bf16
    __shared__ unsigned short As_lo[64 * 40];

    const int tid = threadIdx.x;
    const int ilo = max(0, d - (kN - 1));
    const int cell = blockIdx.x / 20;
    const int nc   = blockIdx.x % 20;
    const int i = ilo + cell;
    const int j = d - i;
    const int w = tid >> 6, lane = tid & 63;
    const int hp = (d + 1) & 1;                  // h plane written at diag d-1

    const int ms = tid >> 3;                     // staging row 0..31 (+g*32)
    const int k4 = (tid & 7) * 4;

    f32x16 acc;
    #pragma unroll
    for (int r = 0; r < 16; ++r) acc[r] = 0.f;

    const int ntile = nc * 2 + (w >> 1);         // global 32-col tile
    const int mt = w & 1;                        // m-tile (rows mt*32..)

    bf16x8 wh_c[2], wl_c[2];                     // [k-half]
    #pragma unroll
    for (int kh = 0; kh < 2; ++kh) {
        const size_t g = (size_t)(ntile * 48 + kh) * 64 + lane;
        wh_c[kh] = *(const bf16x8*)(whi + g * 8);
        wl_c[kh] = *(const bf16x8*)(wlo + g * 8);
    }

    for (int kc = 0; kc < 24; ++kc) {
        // ---- stage A chunk: rows 0..63 (= batch), k = kc*32 .. +31 ----
        #pragma unroll
        for (int g = 0; g < 2; ++g) {
            const int b = g * 32 + ms;
            ushort4 hi4, lo4;
            if (kc < 8) {
                const float4 v = *(const float4*)(x + (((size_t)b * kM + i) * kN + j) * kD + kc * 32 + k4);
                split1(v.x, hi4.x, lo4.x); split1(v.y, hi4.y, lo4.y);
                split1(v.z, hi4.z, lo4.z); split1(v.w, hi4.w, lo4.w);
            } else if (kc < 16) {
                const int u = (kc - 8) * 32 + k4;
                if (j > 0) {
                    const size_t o = (((size_t)hp * kM + i) * kB + b) * kH + u;
                    hi4 = *(const ushort4*)(hhi + o); lo4 = *(const ushort4*)(hlo + o);
                } else {
                    hi4 = *(const ushort4*)(h0h + u); lo4 = *(const ushort4*)(h0l + u);
                }
            } else {
                const int u = (kc - 16) * 32 + k4;
                if (i > 0) {
                    const size_t o = (((size_t)hp * kM + (i - 1)) * kB + b) * kH + u;
                    hi4 = *(const ushort4*)(hhi + o); lo4 = *(const ushort4*)(hlo + o);
                } else {
                    hi4 = *(const ushort4*)(h0h + u); lo4 = *(const ushort4*)(h0l + u);
                }
            }
            *(ushort4*)&As_hi[b * 40 + k4] = hi4;
            *(ushort4*)&As_lo[b * 40 + k4] = lo4;
        }

        // ---- prefetch next chunk's W fragments ----
        bf16x8 wh_n[2], wl_n[2];
        if (kc < 23) {
            #pragma unroll
            for (int kh = 0; kh < 2; ++kh) {
                const size_t g = (size_t)(ntile * 48 + (kc + 1) * 2 + kh) * 64 + lane;
                wh_n[kh] = *(const bf16x8*)(whi + g * 8);
                wl_n[kh] = *(const bf16x8*)(wlo + g * 8);
            }
        }
        __syncthreads();

        // ---- compute: 2 K=16 steps, 3 passes each ----
        #pragma unroll
        for (int kh = 0; kh < 2; ++kh) {
            const int koff = kh * 16 + (lane >> 5) * 8;
            const int m = mt * 32 + (lane & 31);
            const bf16x8 ah = *(const bf16x8*)&As_hi[m * 40 + koff];
            const bf16x8 al = *(const bf16x8*)&As_lo[m * 40 + koff];
            acc = __builtin_amdgcn_mfma_f32_32x32x16_bf16(ah, wh_c[kh], acc, 0, 0, 0);
            acc = __builtin_amdgcn_mfma_f32_32x32x16_bf16(ah, wl_c[kh], acc, 0, 0, 0);
            acc = __builtin_amdgcn_mfma_f32_32x32x16_bf16(al, wh_c[kh], acc, 0, 0, 0);
        }
        __syncthreads();
        #pragma unroll
        for (int kh = 0; kh < 2; ++kh) { wh_c[kh] = wh_n[kh]; wl_c[kh] = wl_n[kh]; }
    }

    // ---- epilogue: C/D layout col=lane&31, row=(r&3)+8*(r>>2)+4*(lane>>5) ----
    const int col = nc * 64 + (w >> 1) * 32 + (lane & 31);
    #pragma unroll
    for (int r = 0; r < 16; ++r) {
        const int mrow = (r & 3) + 8 * (r >> 2) + 4 * (lane >> 5);
        const int b = mt * 32 + mrow;
        gates[((size_t)i * kB + b) * kG5 + col] = acc[r];
    }
}

// ---------------------------------------------------------------------------
// Phase B (per diagonal): cell update + LayerNorm + h_new + head GEMM.
// Block = (cell, 4-batch slice), 256 threads (thread = hidden unit u).
// ---------------------------------------------------------------------------
__global__ __launch_bounds__(256)
void cell_head(int d,
               const float* __restrict__ bg,
               const float* __restrict__ lns,
               const float* __restrict__ lnb,
               const float* __restrict__ Wh,
               const float* __restrict__ bh,
               const float* __restrict__ gates,
               float* __restrict__ c_bufs,
               unsigned short* __restrict__ hhi,
               unsigned short* __restrict__ hlo,
               float* __restrict__ out) {
    __shared__ float hn_s[4 * 256];
    __shared__ float red[8];

    const int tid = threadIdx.x;
    const int ilo = max(0, d - (kN - 1));
    const int i = ilo + (blockIdx.x >> 4);
    const int j = d - i;
    const int b0 = (blockIdx.x & 15) * 4;
    const int plane = kM * kB * kH;
    const float* c_prev = c_bufs + ((d + 1) & 1) * plane;
    float*       c_cur  = c_bufs + (d & 1) * plane;
    const int hp = d & 1;

    const int u = tid;
    const float bg0 = bg[u];
    const float bg1 = bg[kH + u];
    const float bg2 = bg[2 * kH + u];
    const float bg3 = bg[3 * kH + u];
    const float bg4 = bg[4 * kH + u];
    const float lnsc = lns[u];
    const float lnbi = lnb[u];
    const int lane = tid & 63, wid = tid >> 6;

    for (int bl = 0; bl < 4; ++bl) {
        const int b = b0 + bl;
        const float* grow = gates + ((size_t)i * kB + b) * kG5;
        const float fc = grow[u] + bg0;
        const float fr = grow[kH + u] + bg1;
        const float ig = grow[2 * kH + u] + bg2;
        const float og = grow[3 * kH + u] + bg3;
        const float gg = grow[4 * kH + u] + bg4;
        const float cl = (j > 0) ? c_prev[((size_t)i * kB + b) * kH + u] : 0.f;
        const float cu = (i > 0) ? c_prev[((size_t)(i - 1) * kB + b) * kH + u] : 0.f;

        const float cell_v = sigm(fc) * cl + sigm(fr) * cu + sigm(ig) * tanhf(gg);
        c_cur[((size_t)i * kB + b) * kH + u] = cell_v;

        float s = cell_v, s2 = cell_v * cell_v;
        #pragma unroll
        for (int off = 32; off; off >>= 1) {
            s  += __shfl_down(s,  off, 64);
            s2 += __shfl_down(s2, off, 64);
        }
        if (lane == 0) { red[wid] = s; red[4 + wid] = s2; }
        __syncthreads();
        const float sum = red[0] + red[1] + red[2] + red[3];
        const float sq  = red[4] + red[5] + red[6] + red[7];
        __syncthreads();

        const float mu   = sum * (1.f / kH);
        const float var  = sq * (1.f / kH) - mu * mu;
        const float rstd = rsqrtf(var + 1e-6f);
        const float hv   = sigm(og) * tanhf((cell_v - mu) * rstd * lnsc + lnbi);
        hn_s[bl * 256 + u] = hv;
        unsigned short hb, lb;
        split1(hv, hb, lb);
        const size_t ho = (((size_t)hp * kM + i) * kB + b) * kH + u;
        hhi[ho] = hb; hlo[ho] = lb;
    }
    __syncthreads();

    // head: per-wave register copy of hn, readlane broadcast in k-loop
    float hr[4][4];
    #pragma unroll
    for (int bl = 0; bl < 4; ++bl)
        #pragma unroll
        for (int k6 = 0; k6 < 4; ++k6)
            hr[bl][k6] = hn_s[bl * 256 + k6 * 64 + lane];

    const float bhv = bh[u];
    float ah[4];
    #pragma unroll
    for (int bl = 0; bl < 4; ++bl) ah[bl] = bhv;

    #pragma unroll
    for (int k6 = 0; k6 < 4; ++k6) {
        for (int kl = 0; kl < 64; ++kl) {
            const float wv = Wh[(size_t)(k6 * 64 + kl) * kD + u];
            #pragma unroll
            for (int bl = 0; bl < 4; ++bl) {
#if __has_builtin(__builtin_amdgcn_readlane)
                const float hvv = __int_as_float(__builtin_amdgcn_readlane(__float_as_int(hr[bl][k6]), kl));
#else
                const float hvv = __shfl(hr[bl][k6], kl, 64);
#endif
                ah[bl] = fmaf(hvv, wv, ah[bl]);
            }
        }
    }
    #pragma unroll
    for (int bl = 0; bl < 4; ++bl) {
        const int b = b0 + bl;
        out[(((size_t)b * kM + i) * kN + j) * kD + u] = ah[bl];
    }
}

extern "C" void kernel_launch(void* const* d_in, const int* in_sizes, int n_in,
                              void* d_out, int out_size, void* d_ws, size_t ws_size,
                              hipStream_t stream) {
    const float* x     = (const float*)d_in[0];
    const float* Wg    = (const float*)d_in[1];
    const float* bg    = (const float*)d_in[2];
    const float* lns   = (const float*)d_in[3];
    const float* lnb   = (const float*)d_in[4];
    const float* Wh    = (const float*)d_in[5];
    const float* bh    = (const float*)d_in[6];
    const float* hinit = (const float*)d_in[7];
    float* out = (float*)d_out;

    // ws layout (byte offsets, all 16B-aligned); total ~21.8 MB
    char* wsb = (char*)d_ws;
    float*          gates  = (float*)(wsb);                              // 10,485,760 B
    float*          c_bufs = (float*)(wsb + 10485760);                   //  4,194,304 B
    unsigned short* hhi    = (unsigned short*)(wsb + 14680064);          //  2,097,152 B
    unsigned short* hlo    = (unsigned short*)(wsb + 16777216);          //  2,097,152 B
    unsigned short* whi    = (unsigned short*)(wsb + 18874368);          //  1,966,080 B
    unsigned short* wlo    = (unsigned short*)(wsb + 20840448);          //  1,966,080 B
    unsigned short* h0h    = (unsigned short*)(wsb + 22806528);          //        512 B
    unsigned short* h0l    = (unsigned short*)(wsb + 22807040);          //        512 B

    hipLaunchKernelGGL(prep_w, dim3(480), dim3(256), 0, stream, Wg, whi, wlo);
    hipLaunchKernelGGL(prep_h0, dim3(1), dim3(256), 0, stream, hinit, h0h, h0l);

    for (int d = 0; d < kM + kN - 1; ++d) {
        const int ilo = max(0, d - (kN - 1));
        const int ihi = min(d, kM - 1);
        const int ncell = ihi - ilo + 1;
        hipLaunchKernelGGL(gate_mfma, dim3(ncell * 20), dim3(256), 0, stream,
                           d, x, whi, wlo, hhi, hlo, h0h, h0l, gates);
        hipLaunchKernelGGL(cell_head, dim3(ncell * 16), dim3(256), 0, stream,
                           d, bg, lns, lnb, Wh, bh, gates, c_bufs, hhi, hlo, out);
    }
}